// Round 8
// baseline (1758.762 us; speedup 1.0000x reference)
//
#include <hip/hip_runtime.h>

typedef _Float16 f16;
typedef __attribute__((ext_vector_type(8))) _Float16 f16x8;
typedef __attribute__((ext_vector_type(4))) _Float16 f16x4;
typedef __attribute__((ext_vector_type(4))) float f32x4;

#define D_      300
#define DP      320          // padded f16 row width
#define L_      5
#define MAXN_   96
#define NGRAPH  4096
#define MAXDEG  32

// ---------------- weight prep: transpose + pad + f32->f16 ----------------
// W1t[l][j<640][k<320] = W1[l][k][j];  W2t[l][c<304][k<640] = W2[l][k][c]
__global__ void k_prep_w(const float* __restrict__ W1, const float* __restrict__ W2,
                         f16* __restrict__ W1t, f16* __restrict__ W2t) {
  const int T1 = L_ * 640 * 320;
  const int T2 = L_ * 304 * 640;
  for (int idx = blockIdx.x * blockDim.x + threadIdx.x; idx < T1 + T2;
       idx += gridDim.x * blockDim.x) {
    if (idx < T1) {
      int l = idx / (640 * 320), r = idx % (640 * 320);
      int j = r / 320, k = r % 320;
      W1t[idx] = (j < 600 && k < 300) ? (f16)W1[(l * 300 + k) * 600 + j] : (f16)0.0f;
    } else {
      int i2 = idx - T1;
      int l = i2 / (304 * 640), r = i2 % (304 * 640);
      int c = r / 640, k = r % 640;
      W2t[i2] = (c < 300 && k < 600) ? (f16)W2[(l * 600 + k) * 300 + c] : (f16)0.0f;
    }
  }
}

// ---------------- combined edge embedding: eemb[l][code<13][d<304] f32 -------
__global__ void k_prep_eemb(const float* __restrict__ ee1, const float* __restrict__ ee2,
                            float* __restrict__ eemb) {
  int total = L_ * 13 * 304;
  for (int idx = blockIdx.x * blockDim.x + threadIdx.x; idx < total;
       idx += gridDim.x * blockDim.x) {
    int l = idx / (13 * 304), r = idx % (13 * 304);
    int c = r / 304, d = r % 304;
    int bond = (c == 12) ? 4 : (c / 3);
    int dir  = (c == 12) ? 0 : (c % 3);
    eemb[idx] = (d < 300) ? ee1[(l * 6 + bond) * 300 + d] + ee2[(l * 3 + dir) * 300 + d]
                          : 0.0f;
  }
}

// ---------------- graph bookkeeping ----------------
__global__ void k_bc_init(int* counts, int* offsets) {
  int i = blockIdx.x * blockDim.x + threadIdx.x;
  if (i < NGRAPH) { counts[i] = 0; offsets[i] = 0x7fffffff; }
}
__global__ void k_zero_i32(int* p, int n) {
  for (int i = blockIdx.x * blockDim.x + threadIdx.x; i < n; i += gridDim.x * blockDim.x)
    p[i] = 0;
}
__global__ void k_bc_count(const int* __restrict__ batch, int n, int* counts, int* offsets) {
  int i = blockIdx.x * blockDim.x + threadIdx.x;
  if (i < n) { int b = batch[i]; atomicAdd(&counts[b], 1); atomicMin(&offsets[b], i); }
}
__global__ void k_pos(const int* __restrict__ batch, const int* __restrict__ offsets,
                      int n, int* __restrict__ pos) {
  int i = blockIdx.x * blockDim.x + threadIdx.x;
  if (i < n) pos[i] = i - offsets[batch[i]];
}
__global__ void k_mask(const int* __restrict__ counts, float* __restrict__ mask) {
  int i = blockIdx.x * blockDim.x + threadIdx.x;
  if (i < NGRAPH * MAXN_) {
    int b = i / MAXN_, j = i % MAXN_;
    mask[i] = (j >= counts[b]) ? 1.0f : 0.0f;
  }
}
__global__ void k_zero(uint4* __restrict__ p, long nchunks) {
  for (long i = blockIdx.x * (long)blockDim.x + threadIdx.x; i < nchunks;
       i += (long)gridDim.x * blockDim.x)
    p[i] = make_uint4(0u, 0u, 0u, 0u);
}

// ---------------- packed per-dst edge table: epack = src | code<<17 ----------
__global__ void k_epack(const int* __restrict__ src, const int* __restrict__ dst,
                        const int* __restrict__ ea, int ne,
                        int* __restrict__ deg, int* __restrict__ epack) {
  int e = blockIdx.x * blockDim.x + threadIdx.x;
  if (e < ne) {
    int t = dst[e];
    int p = atomicAdd(&deg[t], 1);
    if (p < MAXDEG) epack[t * MAXDEG + p] = src[e] | ((ea[2 * e] * 3 + ea[2 * e + 1]) << 17);
  }
}

// ---------------- h0 = atom_emb1[x0] + atom_emb2[x1] -> f16 [N][320] ---------
__global__ void k_init_h(const int* __restrict__ x, const float* __restrict__ ae1,
                         const float* __restrict__ ae2, f16* __restrict__ h, int n) {
  long total = (long)n * DP;
  for (long idx = blockIdx.x * (long)blockDim.x + threadIdx.x; idx < total;
       idx += (long)gridDim.x * blockDim.x) {
    int i = idx / DP, d = idx % DP;
    if (d < 300) {
      int a1 = x[2 * i], a2 = x[2 * i + 1];
      h[idx] = (f16)(ae1[a1 * 300 + d] + ae2[a2 * 300 + d]);
    } else h[idx] = (f16)0.0f;
  }
}

// ---------------- gather: agg[n] = h[n] + self-emb + sum_in (h[src]+eemb) ----
__launch_bounds__(512)
__global__ void k_gather(const f16* __restrict__ hin, f16* __restrict__ agg,
                         const int* __restrict__ deg, const int* __restrict__ epack,
                         const float* __restrict__ em, int n) {
  int w = threadIdx.x >> 6, lane = threadIdx.x & 63;
  int node = blockIdx.x * 8 + w;
  if (node >= n) return;
  float acc[5];
  const float* ems = em + 12 * 304;               // self-loop row (bond 4, dir 0)
#pragma unroll
  for (int k = 0; k < 5; k++) {
    int d = lane + 64 * k;
    acc[k] = (d < 300) ? (float)hin[node * DP + d] + ems[d] : 0.0f;
  }
  int dg = deg[node]; if (dg > MAXDEG) dg = MAXDEG;
  for (int j = 0; j < dg; j++) {
    int v = epack[node * MAXDEG + j];
    int s = v & 0x1FFFF, c = v >> 17;
    const f16* hr = hin + s * DP;
    const float* er = em + c * 304;
#pragma unroll
    for (int k = 0; k < 5; k++) {
      int d = lane + 64 * k;
      if (d < 300) acc[k] += (float)hr[d] + er[d];
    }
  }
#pragma unroll
  for (int k = 0; k < 5; k++) {
    int d = lane + 64 * k;
    agg[node * DP + d] = (f16)((d < 300) ? acc[k] : 0.0f);
  }
}

// ---------------- fused MLP: h = BN(relu(agg@W1+b1)@W2+b2) [+relu] -----------
// 64 nodes/block, 512 threads (8 waves), LDS 120KB -> 1 block/CU, 2 waves/SIMD.
// j-outer, ONE live accumulator (no spill). NEW (round 8): explicit double-
// buffered weight prefetch — round 7 showed VGPR=88 (budget 256 at 2 w/SIMD):
// compiler was NOT prefetching, each j-tile ate ~200cyc exposed L2 latency.
// GEMM1: bnxt[10] issued before j's MFMAs. GEMM2: bA/bB K-half buffers.
template<int LAST>
__launch_bounds__(512)
__global__ void k_mlp(const f16* agg,              // [N][320]; also hout (in-place)
                      f16* hout,
                      const f16* __restrict__ W1t, // [640][320]
                      const f16* __restrict__ W2t, // [304][640]
                      const float* __restrict__ b1, const float* __restrict__ b2,
                      const float* __restrict__ bng, const float* __restrict__ bnb,
                      const float* __restrict__ bnm, const float* __restrict__ bnv,
                      float* __restrict__ outp, const int* __restrict__ batch,
                      const int* __restrict__ pos) {
  __shared__ __align__(16) unsigned char smem[122880];
  f16* As = (f16*)smem;              // [64][320] swizzled, 40960 B (dead after GEMM1)
  f16* Hs = (f16*)(smem + 40960);    // [64][640] swizzled, 81920 B
  f16* Os = (f16*)smem;              // epilogue bounce (overlays As)

  const int tid = threadIdx.x, w = tid >> 6, lane = tid & 63;
  const int lr = lane & 15, lk = lane >> 4;
  const int n0 = blockIdx.x * 64;

  // ---- stage A: 2560 16B-chunks, coalesced global read -> swizzled ds_write
#pragma unroll
  for (int q = 0; q < 5; q++) {
    int c = q * 512 + tid;
    int row = c / 40, cc = c % 40;
    f16x8 v = *(const f16x8*)(agg + (size_t)(n0 + row) * DP + cc * 8);
    *(f16x8*)(As + row * 320 + ((cc ^ (row & 7)) << 3)) = v;
  }
  __syncthreads();

  // ---- GEMM1: Hs = relu(As @ W1 + b1); 40 col-tiles = 5/wave, dbuf prefetch
  {
    const f16* wbase = W1t + (size_t)(w * 16 + lr) * 320 + lk * 8;
    f16x8 bcur[10], bnxt[10];
#pragma unroll
    for (int ks = 0; ks < 10; ks++) bcur[ks] = *(const f16x8*)(wbase + ks * 32);
#pragma unroll
    for (int j = 0; j < 5; j++) {
      const int col = (w + 8 * j) * 16 + lr;    // 0..639
      if (j < 4) {
        const f16* wb2 = wbase + (size_t)(j + 1) * 128 * 320;
#pragma unroll
        for (int ks = 0; ks < 10; ks++) bnxt[ks] = *(const f16x8*)(wb2 + ks * 32);
      }
      f32x4 a1[4] = {};
#pragma unroll
      for (int ks = 0; ks < 10; ks++) {
        int kc = ks * 4 + lk;
#pragma unroll
        for (int rg = 0; rg < 4; rg++) {
          int row = rg * 16 + lr;
          f16x8 af = *(const f16x8*)(As + row * 320 + ((kc ^ (row & 7)) << 3));
          a1[rg] = __builtin_amdgcn_mfma_f32_16x16x32_f16(af, bcur[ks], a1[rg], 0, 0, 0);
        }
      }
      float bv = (col < 600) ? b1[col] : 0.0f;
      int chq = col >> 3, cof = col & 7;
#pragma unroll
      for (int rg = 0; rg < 4; rg++)
#pragma unroll
        for (int i = 0; i < 4; i++) {
          int row = rg * 16 + lk * 4 + i;
          Hs[row * 640 + (((chq ^ (row & 7)) << 3) | cof)] =
              (f16)fmaxf(a1[rg][i] + bv, 0.0f);
        }
#pragma unroll
      for (int ks = 0; ks < 10; ks++) bcur[ks] = bnxt[ks];
    }
  }
  __syncthreads();

  // ---- GEMM2: out = BN(Hs @ W2 + b2); 19 col-tiles, K=640, j-outer,
  //      K-half double-buffer (bA: ks 0..9, bB: ks 10..19)
  {
    // per-j W2 row base (clamped so prefetch for masked tiles stays in-bounds)
    const f16* w2b[4];
#pragma unroll
    for (int j = 0; j < 3; j++) {
      int ct = w + 8 * j; if (ct > 18) ct = 18;
      w2b[j] = W2t + (size_t)(ct * 16 + lr) * 640 + lk * 8;
    }
    w2b[3] = w2b[2];
    f16x8 bA[10], bB[10];
#pragma unroll
    for (int ks = 0; ks < 10; ks++) bA[ks] = *(const f16x8*)(w2b[0] + ks * 32);
#pragma unroll
    for (int j = 0; j < 3; j++) {
      const int ct = w + 8 * j;
      if (ct < 19) {
        const int col = ct * 16 + lr;
        // issue second K-half for this j
#pragma unroll
        for (int ks = 0; ks < 10; ks++) bB[ks] = *(const f16x8*)(w2b[j] + 320 + ks * 32);
        f32x4 c2[4] = {};
#pragma unroll
        for (int ks = 0; ks < 10; ks++) {
          int kc = ks * 4 + lk;
#pragma unroll
          for (int rg = 0; rg < 4; rg++) {
            int row = rg * 16 + lr;
            f16x8 hf = *(const f16x8*)(Hs + row * 640 + ((kc ^ (row & 7)) << 3));
            c2[rg] = __builtin_amdgcn_mfma_f32_16x16x32_f16(hf, bA[ks], c2[rg], 0, 0, 0);
          }
        }
        // issue first K-half for j+1
        if (j < 2) {
#pragma unroll
          for (int ks = 0; ks < 10; ks++) bA[ks] = *(const f16x8*)(w2b[j + 1] + ks * 32);
        }
#pragma unroll
        for (int ks = 10; ks < 20; ks++) {
          int kc = ks * 4 + lk;
#pragma unroll
          for (int rg = 0; rg < 4; rg++) {
            int row = rg * 16 + lr;
            f16x8 hf = *(const f16x8*)(Hs + row * 640 + ((kc ^ (row & 7)) << 3));
            c2[rg] = __builtin_amdgcn_mfma_f32_16x16x32_f16(hf, bB[ks - 10], c2[rg], 0, 0, 0);
          }
        }
        bool real = col < 300;
        float b2v = real ? b2[col] : 0.0f;
        float sc  = real ? bng[col] * rsqrtf(bnv[col] + 1e-5f) : 0.0f;
        float mu  = real ? bnm[col] : 0.0f;
        float be  = real ? bnb[col] : 0.0f;
        int chq = col >> 3, cof = col & 7;
#pragma unroll
        for (int rg = 0; rg < 4; rg++)
#pragma unroll
          for (int i = 0; i < 4; i++) {
            int row = rg * 16 + lk * 4 + i;
            float v = (c2[rg][i] + b2v - mu) * sc + be;
            if (!LAST) v = fmaxf(v, 0.0f);
            Os[row * 320 + (((chq ^ (row & 7)) << 3) | cof)] =
                real ? (f16)v : (f16)0.0f;
          }
      }
    }
  }

  // zero pad chunks 38,39 (cols 304..319)
  if (tid < 128) {
    int row = tid >> 1, cc = 38 + (tid & 1);
    f16x8 zz = {};
    *(f16x8*)(Os + row * 320 + ((cc ^ (row & 7)) << 3)) = zz;
  }
  __syncthreads();

  if (!LAST) {
#pragma unroll
    for (int q = 0; q < 5; q++) {
      int c = q * 512 + tid;
      int row = c / 40, cc = c % 40;
      *(f16x8*)(hout + (size_t)(n0 + row) * DP + cc * 8) =
          *(const f16x8*)(Os + row * 320 + ((cc ^ (row & 7)) << 3));
    }
  } else {
    // scatter node rows into padded [B][96][300] f32; merged 8B LDS reads
    for (int idx = tid; idx < 64 * 75; idx += 512) {
      int row = idx / 75, c4 = idx % 75;
      int node = n0 + row;
      int g = batch[node], p = pos[node];
      if (p < MAXN_) {
        int col = c4 * 4;
        const f16* s = Os + row * 320 + (((col >> 3) ^ (row & 7)) << 3) + (col & 7);
        f16x4 hv = *(const f16x4*)s;
        float4 v = make_float4((float)hv[0], (float)hv[1], (float)hv[2], (float)hv[3]);
        *(float4*)(outp + ((long)g * MAXN_ + p) * 300 + col) = v;
      }
    }
  }
}

extern "C" void kernel_launch(void* const* d_in, const int* in_sizes, int n_in,
                              void* d_out, int out_size, void* d_ws, size_t ws_size,
                              hipStream_t stream) {
  const int* x     = (const int*)d_in[0];
  const int* ei    = (const int*)d_in[1];
  const int* ea    = (const int*)d_in[2];
  const int* batch = (const int*)d_in[3];
  const float* ae1 = (const float*)d_in[5];
  const float* ae2 = (const float*)d_in[6];
  const float* ee1 = (const float*)d_in[7];
  const float* ee2 = (const float*)d_in[8];
  const float* W1  = (const float*)d_in[9];
  const float* b1  = (const float*)d_in[10];
  const float* W2  = (const float*)d_in[11];
  const float* b2  = (const float*)d_in[12];
  const float* bng = (const float*)d_in[13];
  const float* bnb = (const float*)d_in[14];
  const float* bnm = (const float*)d_in[15];
  const float* bnv = (const float*)d_in[16];

  const int N = in_sizes[3];        // 131072
  const int E = in_sizes[2] / 2;    // 262144

  char* ws = (char*)d_ws;
  f16*   hX    = (f16*)ws;                              //  83,886,080 B
  f16*   hY    = (f16*)(ws + 83886080);                 //  83,886,080 B
  f16*   W1t   = (f16*)(ws + 167772160);                //   2,048,000 B
  f16*   W2t   = (f16*)(ws + 169820160);                //   1,945,600 B
  float* eemb  = (float*)(ws + 171765760);              //      79,040 B
  int*   epack = (int*)(ws + 171844800);                //  16,777,216 B
  int*   deg   = (int*)(ws + 188622016);                //     524,288 B
  int*   pos   = (int*)(ws + 189146304);                //     524,288 B
  int*   counts= (int*)(ws + 189670592);                //      16,384 B
  int*   offs  = (int*)(ws + 189686976);                //      16,384 B  (~190 MB)

  float* outp  = (float*)d_out;
  float* maskp = outp + (long)NGRAPH * MAXN_ * D_;

  hipLaunchKernelGGL(k_prep_w, dim3(2048), dim3(256), 0, stream, W1, W2, W1t, W2t);
  hipLaunchKernelGGL(k_prep_eemb, dim3(80), dim3(256), 0, stream, ee1, ee2, eemb);
  hipLaunchKernelGGL(k_bc_init, dim3(16), dim3(256), 0, stream, counts, offs);
  hipLaunchKernelGGL(k_zero_i32, dim3(512), dim3(256), 0, stream, deg, N);
  hipLaunchKernelGGL(k_bc_count, dim3((N + 255) / 256), dim3(256), 0, stream, batch, N, counts, offs);
  hipLaunchKernelGGL(k_pos, dim3((N + 255) / 256), dim3(256), 0, stream, batch, offs, N, pos);
  hipLaunchKernelGGL(k_mask, dim3((NGRAPH * MAXN_ + 255) / 256), dim3(256), 0, stream, counts, maskp);
  hipLaunchKernelGGL(k_epack, dim3((E + 255) / 256), dim3(256), 0, stream,
                     ei, ei + E, ea, E, deg, epack);
  hipLaunchKernelGGL(k_zero, dim3(4096), dim3(256), 0, stream,
                     (uint4*)outp, (long)NGRAPH * MAXN_ * D_ / 4);
  hipLaunchKernelGGL(k_init_h, dim3(8192), dim3(256), 0, stream, x, ae1, ae2, hX, N);

  for (int l = 0; l < L_; l++) {
    const f16* hi = (l & 1) ? hY : hX;   // ping-pong; mlp writes in-place into agg
    f16*       ag = (l & 1) ? hX : hY;
    hipLaunchKernelGGL(k_gather, dim3(N / 8), dim3(512), 0, stream,
                       hi, ag, deg, epack, eemb + l * 13 * 304, N);
    if (l < L_ - 1)
      hipLaunchKernelGGL((k_mlp<0>), dim3(N / 64), dim3(512), 0, stream,
                         ag, ag,
                         W1t + l * 640 * 320, W2t + l * 304 * 640,
                         b1 + l * 600, b2 + l * 300,
                         bng + l * 300, bnb + l * 300, bnm + l * 300, bnv + l * 300,
                         outp, batch, pos);
    else
      hipLaunchKernelGGL((k_mlp<1>), dim3(N / 64), dim3(512), 0, stream,
                         ag, ag,
                         W1t + l * 640 * 320, W2t + l * 304 * 640,
                         b1 + l * 600, b2 + l * 300,
                         bng + l * 300, bnb + l * 300, bnm + l * 300, bnv + l * 300,
                         outp, batch, pos);
  }
}